// Round 3
// baseline (930.879 us; speedup 1.0000x reference)
//
#include <hip/hip_runtime.h>

#define E_EDGES 1600000
#define BM 64
#define TPB 512
#define NTILES (E_EDGES / BM)   // 25000 exactly
#define GRID 768
#define WOFF 40960              // shorts reserved for weights in d_ws
#define XBF_SHORTS (100000 * 64)

typedef short s16x8 __attribute__((ext_vector_type(8)));
typedef float f32x4 __attribute__((ext_vector_type(4)));

__device__ __forceinline__ unsigned short f2bf(float f) {
    unsigned int u = __builtin_bit_cast(unsigned int, f);
    u += 0x7FFFu + ((u >> 16) & 1u);   // RNE
    return (unsigned short)(u >> 16);
}

__device__ __forceinline__ s16x8 pack8(float4 a, float4 b) {
    s16x8 r;
    r[0] = (short)f2bf(a.x); r[1] = (short)f2bf(a.y);
    r[2] = (short)f2bf(a.z); r[3] = (short)f2bf(a.w);
    r[4] = (short)f2bf(b.x); r[5] = (short)f2bf(b.y);
    r[6] = (short)f2bf(b.z); r[7] = (short)f2bf(b.w);
    return r;
}

// d_ws layout (shorts): [0,16384) Wnnn^T [128o][128i]; [16384,24576) Wroot^T [128o][64i];
//                       [24576,40960) Wout^T [128o][128i]; [40960, +6.4M) x as bf16
__global__ void prep_w(const float* __restrict__ Wn, const float* __restrict__ Wr,
                       const float* __restrict__ Wo, unsigned short* __restrict__ wt) {
    int t = blockIdx.x * 256 + threadIdx.x;
    if (t < 16384) {
        int o = t >> 7, i = t & 127;
        wt[t] = f2bf(Wn[i * 128 + o]);
    } else if (t < 24576) {
        int q = t - 16384;
        int o = q >> 6, i = q & 63;
        wt[t] = f2bf(Wr[i * 128 + o]);
    } else if (t < 40960) {
        int q = t - 24576;
        int o = q >> 7, i = q & 127;
        wt[t] = f2bf(Wo[i * 128 + o]);
    }
}

__global__ void prep_x(const float* __restrict__ x, unsigned short* __restrict__ xb) {
    int i = blockIdx.x * 256 + threadIdx.x;    // 800000 chunks of 8 floats
    if (i < XBF_SHORTS / 8) {
        const float4* p = (const float4*)(x + (size_t)i * 8);
        *(s16x8*)(xb + (size_t)i * 8) = pack8(p[0], p[1]);
    }
}

template<bool XBF>
__global__ __launch_bounds__(TPB, 6) void edge_mlp(
    const float* __restrict__ x, const unsigned short* __restrict__ xb,
    const int* __restrict__ eidx, const float* __restrict__ ea,
    const float* __restrict__ bn_g, const float* __restrict__ br_g,
    const float* __restrict__ bo_g,
    const unsigned short* __restrict__ wt, float* __restrict__ out)
{
    __shared__ unsigned short sh_pair[BM * 128];  // 16 KB, swizzled
    __shared__ unsigned short sh_ea[BM * 64];     //  8 KB, swizzled
    __shared__ unsigned short sh_hid[BM * 128];   // 16 KB, swizzled

    const int tid = threadIdx.x;
    const int ln  = tid & 63;
    const int lc  = ln & 15;
    const int lk8 = (ln >> 4) * 8;
    const int ncol = (tid >> 6) * 16;            // wave's 16-col N-slice

    // gather ownership: thread covers edge-row r, two 16B bf16 chunks of the pair row
    const int r   = tid >> 3;        // 0..63
    const int c2  = (tid & 7) * 2;   // even chunk index 0..14
    const int idx_base = (c2 >= 8) ? E_EDGES : 0;
    const int cloc = (c2 >= 8) ? (c2 - 8) : c2;  // chunk within node row (8 chunks)
    const int ec  = tid & 7;         // ea chunk index

    const unsigned short* Wn = wt;
    const unsigned short* Wr = wt + 16384;
    const unsigned short* Wo = wt + 24576;

    // --- per-wave weight fragments in registers, loaded once ---
    s16x8 wn[4], wr[2], wo[4];
    const int n = ncol + lc;
    #pragma unroll
    for (int ks = 0; ks < 4; ++ks) wn[ks] = *(const s16x8*)(Wn + n * 128 + ks * 32 + lk8);
    #pragma unroll
    for (int ks = 0; ks < 2; ++ks) wr[ks] = *(const s16x8*)(Wr + n * 64 + ks * 32 + lk8);
    #pragma unroll
    for (int ks = 0; ks < 4; ++ks) wo[ks] = *(const s16x8*)(Wo + n * 128 + ks * 32 + lk8);
    const float bn = bn_g[n], br = br_g[n], bo = bo_g[n];

    // --- software pipeline state ---
    s16x8 pb0, pb1;      // XBF: 32B bf16 slice of x[node]
    float4 pf0, pf1, pf2, pf3;  // fallback: 64B fp32 slice
    float4 pe0, pe1;     // 32B slice of edge_attr row
    int idx_n, idx_nn;

    int tile = blockIdx.x;
    if (tile >= NTILES) return;

    idx_n = eidx[idx_base + tile * BM + r];
    {   // issue tile-0 loads
        if constexpr (XBF) {
            const s16x8* xp = (const s16x8*)(xb + (size_t)idx_n * 64 + cloc * 8);
            pb0 = xp[0]; pb1 = xp[1];
        } else {
            const float4* xp = (const float4*)(x + (size_t)idx_n * 64 + cloc * 8);
            pf0 = xp[0]; pf1 = xp[1]; pf2 = xp[2]; pf3 = xp[3];
        }
        const float4* ep = (const float4*)(ea + (size_t)(tile * BM + r) * 64 + ec * 8);
        pe0 = ep[0]; pe1 = ep[1];
    }
    {   // prefetch next tile's index (breaks idx->gather dependent chain)
        int t1 = (tile + GRID < NTILES) ? tile + GRID : tile;
        idx_nn = eidx[idx_base + t1 * BM + r];
    }

    for (; tile < NTILES; tile += GRID) {
        const int base = tile * BM;
        const int tn  = (tile + GRID < NTILES) ? tile + GRID : tile;

        // --- 1. drain prefetch -> bf16 LDS (swizzled) ---
        {
            unsigned o0 = (unsigned)(r * 256 + c2 * 16) ^ (unsigned)((r & 7) << 4);
            unsigned o1 = (unsigned)(r * 256 + (c2 + 1) * 16) ^ (unsigned)((r & 7) << 4);
            if constexpr (XBF) {
                *(s16x8*)((char*)sh_pair + o0) = pb0;
                *(s16x8*)((char*)sh_pair + o1) = pb1;
            } else {
                *(s16x8*)((char*)sh_pair + o0) = pack8(pf0, pf1);
                *(s16x8*)((char*)sh_pair + o1) = pack8(pf2, pf3);
            }
            unsigned oe = (unsigned)(r * 128 + ec * 16) ^ (unsigned)((r & 7) << 4);
            *(s16x8*)((char*)sh_ea + oe) = pack8(pe0, pe1);
        }

        // --- 2. issue next tile's loads (latency hidden under compute) ---
        idx_n = idx_nn;
        if constexpr (XBF) {
            const s16x8* xp = (const s16x8*)(xb + (size_t)idx_n * 64 + cloc * 8);
            pb0 = xp[0]; pb1 = xp[1];
        } else {
            const float4* xp = (const float4*)(x + (size_t)idx_n * 64 + cloc * 8);
            pf0 = xp[0]; pf1 = xp[1]; pf2 = xp[2]; pf3 = xp[3];
        }
        {
            const float4* ep = (const float4*)(ea + (size_t)(tn * BM + r) * 64 + ec * 8);
            pe0 = ep[0]; pe1 = ep[1];
        }
        {
            int tnn = (tn + GRID < NTILES) ? tn + GRID : tn;
            idx_nn = eidx[idx_base + tnn * BM + r];
        }
        __syncthreads();

        // --- 3. layer 1: hidden = relu(pair@Wnnn+bn) + relu(ea@Wroot+br) ---
        #pragma unroll
        for (int m = 0; m < 4; ++m) {
            const int row = m * 16 + lc;
            f32x4 a1 = {0.f, 0.f, 0.f, 0.f};
            f32x4 a2 = {0.f, 0.f, 0.f, 0.f};
            #pragma unroll
            for (int ks = 0; ks < 4; ++ks) {
                unsigned off = (unsigned)(row * 256 + (ks * 32 + lk8) * 2) ^ (unsigned)((row & 7) << 4);
                s16x8 a = *(const s16x8*)((const char*)sh_pair + off);
                a1 = __builtin_amdgcn_mfma_f32_16x16x32_bf16(a, wn[ks], a1, 0, 0, 0);
            }
            #pragma unroll
            for (int ks = 0; ks < 2; ++ks) {
                unsigned off = (unsigned)(row * 128 + (ks * 32 + lk8) * 2) ^ (unsigned)((row & 7) << 4);
                s16x8 a = *(const s16x8*)((const char*)sh_ea + off);
                a2 = __builtin_amdgcn_mfma_f32_16x16x32_bf16(a, wr[ks], a2, 0, 0, 0);
            }
            #pragma unroll
            for (int j = 0; j < 4; ++j) {
                float h = fmaxf(a1[j] + bn, 0.f) + fmaxf(a2[j] + br, 0.f);
                int hr = m * 16 + (ln >> 4) * 4 + j;
                int hc = ncol + lc;
                unsigned off = (unsigned)(hr * 256 + hc * 2) ^ (unsigned)((hr & 7) << 4);
                *(unsigned short*)((char*)sh_hid + off) = f2bf(h);
            }
        }
        __syncthreads();

        // --- 4. layer 2: out = relu(hidden@Wout+bo), nontemporal stores ---
        #pragma unroll
        for (int m = 0; m < 4; ++m) {
            const int row = m * 16 + lc;
            f32x4 a3 = {0.f, 0.f, 0.f, 0.f};
            #pragma unroll
            for (int ks = 0; ks < 4; ++ks) {
                unsigned off = (unsigned)(row * 256 + (ks * 32 + lk8) * 2) ^ (unsigned)((row & 7) << 4);
                s16x8 a = *(const s16x8*)((const char*)sh_hid + off);
                a3 = __builtin_amdgcn_mfma_f32_16x16x32_bf16(a, wo[ks], a3, 0, 0, 0);
            }
            #pragma unroll
            for (int j = 0; j < 4; ++j) {
                float o = fmaxf(a3[j] + bo, 0.f);
                int orow = base + m * 16 + (ln >> 4) * 4 + j;
                __builtin_nontemporal_store(o, out + (size_t)orow * 128 + (size_t)(ncol + lc));
            }
        }
        // barrier discipline (2/tile): pair/ea rewrites are ordered after all L1
        // reads by the hid barrier; hid rewrites ordered after L2 reads by the
        // next iteration's post-gather barrier.
    }
}

extern "C" void kernel_launch(void* const* d_in, const int* in_sizes, int n_in,
                              void* d_out, int out_size, void* d_ws, size_t ws_size,
                              hipStream_t stream) {
    const float* x   = (const float*)d_in[0];
    const int*   ei  = (const int*)d_in[1];
    const float* ea  = (const float*)d_in[2];
    const float* Wn  = (const float*)d_in[3];
    const float* bn  = (const float*)d_in[4];
    const float* Wr  = (const float*)d_in[5];
    const float* br  = (const float*)d_in[6];
    const float* Wo  = (const float*)d_in[7];
    const float* bo  = (const float*)d_in[8];
    float* out = (float*)d_out;
    unsigned short* wt = (unsigned short*)d_ws;

    const bool xbf = ws_size >= (size_t)(WOFF + XBF_SHORTS) * sizeof(unsigned short);

    prep_w<<<160, 256, 0, stream>>>(Wn, Wr, Wo, wt);
    if (xbf) {
        prep_x<<<(XBF_SHORTS / 8 + 255) / 256, 256, 0, stream>>>(x, wt + WOFF);
        edge_mlp<true><<<GRID, TPB, 0, stream>>>(x, wt + WOFF, ei, ea, bn, br, bo, wt, out);
    } else {
        edge_mlp<false><<<GRID, TPB, 0, stream>>>(x, nullptr, ei, ea, bn, br, bo, wt, out);
    }
}

// Round 4
// 553.326 us; speedup vs baseline: 1.6823x; 1.6823x over previous
//
#include <hip/hip_runtime.h>

#define E_EDGES 1600000
#define BM 64
#define TPB 512
#define NTILES (E_EDGES / BM)   // 25000 exactly
#define GRID 512
#define WOFF 40960              // shorts reserved for weights in d_ws
#define XBF_SHORTS (100000 * 64)

typedef short s16x8 __attribute__((ext_vector_type(8)));
typedef float f32x4 __attribute__((ext_vector_type(4)));

__device__ __forceinline__ unsigned short f2bf(float f) {
    unsigned int u = __builtin_bit_cast(unsigned int, f);
    u += 0x7FFFu + ((u >> 16) & 1u);   // RNE
    return (unsigned short)(u >> 16);
}

__device__ __forceinline__ s16x8 pack8(float4 a, float4 b) {
    s16x8 r;
    r[0] = (short)f2bf(a.x); r[1] = (short)f2bf(a.y);
    r[2] = (short)f2bf(a.z); r[3] = (short)f2bf(a.w);
    r[4] = (short)f2bf(b.x); r[5] = (short)f2bf(b.y);
    r[6] = (short)f2bf(b.z); r[7] = (short)f2bf(b.w);
    return r;
}

// d_ws layout (shorts): [0,16384) Wnnn^T [128o][128i]; [16384,24576) Wroot^T [128o][64i];
//                       [24576,40960) Wout^T [128o][128i]; [40960, +6.4M) x as bf16
__global__ void prep_w(const float* __restrict__ Wn, const float* __restrict__ Wr,
                       const float* __restrict__ Wo, unsigned short* __restrict__ wt) {
    int t = blockIdx.x * 256 + threadIdx.x;
    if (t < 16384) {
        int o = t >> 7, i = t & 127;
        wt[t] = f2bf(Wn[i * 128 + o]);
    } else if (t < 24576) {
        int q = t - 16384;
        int o = q >> 6, i = q & 63;
        wt[t] = f2bf(Wr[i * 128 + o]);
    } else if (t < 40960) {
        int q = t - 24576;
        int o = q >> 7, i = q & 127;
        wt[t] = f2bf(Wo[i * 128 + o]);
    }
}

__global__ void prep_x(const float* __restrict__ x, unsigned short* __restrict__ xb) {
    int i = blockIdx.x * 256 + threadIdx.x;    // 800000 chunks of 8 floats
    if (i < XBF_SHORTS / 8) {
        const float4* p = (const float4*)(x + (size_t)i * 8);
        *(s16x8*)(xb + (size_t)i * 8) = pack8(p[0], p[1]);
    }
}

// Swapped-operand MFMA scheme: mfma(A = W^T frag [n][k], B = data^T frag [k][e]).
// A-frag: row = lane&15 -> n ; B-frag: col = lane&15 -> e ; both k = (lane>>4)*8+j.
// C-frag: col = lane&15 -> e ; row = (lane>>4)*4+j -> n  => 4 CONSECUTIVE n per lane:
// hid LDS writes are b64, out global stores are dwordx4.
template<bool XBF>
__global__ __launch_bounds__(TPB, 4) void edge_mlp(
    const float* __restrict__ x, const unsigned short* __restrict__ xb,
    const int* __restrict__ eidx, const float* __restrict__ ea,
    const float* __restrict__ bn_g, const float* __restrict__ br_g,
    const float* __restrict__ bo_g,
    const unsigned short* __restrict__ wt, float* __restrict__ out)
{
    __shared__ unsigned short sh_ea[BM * 64];    // [e][k] bf16, swz, 8 KB
    __shared__ unsigned short sh_hid[BM * 128];  // [e][n] bf16, swz, 16 KB

    const int tid = threadIdx.x;
    const int w   = tid >> 6;        // wave 0..7 -> n-slice w*16
    const int ln  = tid & 63;
    const int lc  = ln & 15;
    const int q   = ln >> 4;         // 0..3
    const int lk8 = q * 8;

    const unsigned short* Wn = wt;
    const unsigned short* Wr = wt + 16384;
    const unsigned short* Wo = wt + 24576;

    // --- pinned weight A-fragments (40 VGPR) ---
    s16x8 wn[4], wr[2], wo[4];
    const int n0 = w * 16 + lc;
    #pragma unroll
    for (int kk = 0; kk < 4; ++kk) wn[kk] = *(const s16x8*)(Wn + n0 * 128 + kk * 32 + lk8);
    #pragma unroll
    for (int kk = 0; kk < 2; ++kk) wr[kk] = *(const s16x8*)(Wr + n0 * 64 + kk * 32 + lk8);
    #pragma unroll
    for (int kk = 0; kk < 4; ++kk) wo[kk] = *(const s16x8*)(Wo + n0 * 128 + kk * 32 + lk8);

    // --- bias vectors at this lane's 4 consecutive n ---
    const int nb = w * 16 + q * 4;
    const float4 bn4 = *(const float4*)(bn_g + nb);
    const float4 br4 = *(const float4*)(br_g + nb);
    const float4 bo4 = *(const float4*)(bo_g + nb);

    // ea gather ownership: thread owns row er, 8-float segment es
    const int er = tid >> 3;         // 0..63
    const int es = tid & 7;          // 0..7

    float4 pe0, pe1;                 // cross-tile ea prefetch (HBM stream)
    int tile = blockIdx.x;

    {   // prologue: ea for tile 0
        const float4* ep = (const float4*)(ea + (size_t)(tile * BM + er) * 64 + es * 8);
        pe0 = ep[0]; pe1 = ep[1];
    }

    for (; tile < NTILES; tile += GRID) {
        const int base = tile * BM;

        // A: drain ea prefetch -> sh_ea  (safe vs prev-iter reads: they ended
        //    before prev barrier2, and we are past it)
        {
            unsigned off = (unsigned)(er * 128 + es * 16) ^ (unsigned)((er & 7) << 4);
            *(s16x8*)((char*)sh_ea + off) = pack8(pe0, pe1);
        }

        // B: edge indices for THIS tile (L1/L2-hit, consumed after barrier)
        int isrc[4], idst[4];
        #pragma unroll
        for (int m = 0; m < 4; ++m) {
            isrc[m] = eidx[base + m * 16 + lc];
            idst[m] = eidx[E_EDGES + base + m * 16 + lc];
        }

        // C: issue ea loads for next tile (latency hidden under full tile)
        {
            int tn = (tile + GRID < NTILES) ? tile + GRID : tile;
            const float4* ep = (const float4*)(ea + (size_t)(tn * BM + er) * 64 + es * 8);
            pe0 = ep[0]; pe1 = ep[1];
        }
        __syncthreads();   // barrier1: sh_ea writes -> L1 reads; sh_hid F(t-1) reads -> D(t) writes

        // D: layer 1 -> sh_hid
        #pragma unroll
        for (int m = 0; m < 4; ++m) {
            const int e = m * 16 + lc;
            f32x4 a1 = {0.f, 0.f, 0.f, 0.f};
            f32x4 a2 = {0.f, 0.f, 0.f, 0.f};
            if constexpr (XBF) {
                s16x8 f0 = *(const s16x8*)(xb + (size_t)isrc[m] * 64 + lk8);
                s16x8 f1 = *(const s16x8*)(xb + (size_t)isrc[m] * 64 + 32 + lk8);
                s16x8 f2 = *(const s16x8*)(xb + (size_t)idst[m] * 64 + lk8);
                s16x8 f3 = *(const s16x8*)(xb + (size_t)idst[m] * 64 + 32 + lk8);
                a1 = __builtin_amdgcn_mfma_f32_16x16x32_bf16(wn[0], f0, a1, 0, 0, 0);
                a1 = __builtin_amdgcn_mfma_f32_16x16x32_bf16(wn[1], f1, a1, 0, 0, 0);
                a1 = __builtin_amdgcn_mfma_f32_16x16x32_bf16(wn[2], f2, a1, 0, 0, 0);
                a1 = __builtin_amdgcn_mfma_f32_16x16x32_bf16(wn[3], f3, a1, 0, 0, 0);
            } else {
                const float4* ps = (const float4*)(x + (size_t)isrc[m] * 64 + lk8);
                const float4* pd = (const float4*)(x + (size_t)idst[m] * 64 + lk8);
                s16x8 f0 = pack8(ps[0], ps[1]);
                s16x8 f1 = pack8(ps[8], ps[9]);    // +32 floats = +8 float4
                s16x8 f2 = pack8(pd[0], pd[1]);
                s16x8 f3 = pack8(pd[8], pd[9]);
                a1 = __builtin_amdgcn_mfma_f32_16x16x32_bf16(wn[0], f0, a1, 0, 0, 0);
                a1 = __builtin_amdgcn_mfma_f32_16x16x32_bf16(wn[1], f1, a1, 0, 0, 0);
                a1 = __builtin_amdgcn_mfma_f32_16x16x32_bf16(wn[2], f2, a1, 0, 0, 0);
                a1 = __builtin_amdgcn_mfma_f32_16x16x32_bf16(wn[3], f3, a1, 0, 0, 0);
            }
            #pragma unroll
            for (int kk = 0; kk < 2; ++kk) {
                unsigned off = (unsigned)(e * 128 + kk * 64 + q * 16) ^ (unsigned)((e & 7) << 4);
                s16x8 g = *(const s16x8*)((const char*)sh_ea + off);
                a2 = __builtin_amdgcn_mfma_f32_16x16x32_bf16(wr[kk], g, a2, 0, 0, 0);
            }
            // h_j = relu(a1_j + bn) + relu(a2_j + br), j -> 4 consecutive n
            unsigned short h0 = f2bf(fmaxf(a1[0] + bn4.x, 0.f) + fmaxf(a2[0] + br4.x, 0.f));
            unsigned short h1 = f2bf(fmaxf(a1[1] + bn4.y, 0.f) + fmaxf(a2[1] + br4.y, 0.f));
            unsigned short h2 = f2bf(fmaxf(a1[2] + bn4.z, 0.f) + fmaxf(a2[2] + br4.z, 0.f));
            unsigned short h3 = f2bf(fmaxf(a1[3] + bn4.w, 0.f) + fmaxf(a2[3] + br4.w, 0.f));
            uint2 hv;
            hv.x = (unsigned)h0 | ((unsigned)h1 << 16);
            hv.y = (unsigned)h2 | ((unsigned)h3 << 16);
            unsigned hoff = (unsigned)(e * 256 + w * 32 + q * 8) ^ (unsigned)((e & 7) << 4);
            *(uint2*)((char*)sh_hid + hoff) = hv;
        }
        __syncthreads();   // barrier2: sh_hid writes -> L2 reads

        // F: layer 2 -> out (dwordx4 stores: 4 consecutive n at fixed edge)
        #pragma unroll
        for (int m = 0; m < 4; ++m) {
            const int e = m * 16 + lc;
            f32x4 a3 = {0.f, 0.f, 0.f, 0.f};
            #pragma unroll
            for (int kk = 0; kk < 4; ++kk) {
                unsigned off = (unsigned)(e * 256 + kk * 64 + q * 16) ^ (unsigned)((e & 7) << 4);
                s16x8 g = *(const s16x8*)((const char*)sh_hid + off);
                a3 = __builtin_amdgcn_mfma_f32_16x16x32_bf16(wo[kk], g, a3, 0, 0, 0);
            }
            float4 o;
            o.x = fmaxf(a3[0] + bo4.x, 0.f);
            o.y = fmaxf(a3[1] + bo4.y, 0.f);
            o.z = fmaxf(a3[2] + bo4.z, 0.f);
            o.w = fmaxf(a3[3] + bo4.w, 0.f);
            *(float4*)(out + (size_t)(base + e) * 128 + nb) = o;
        }
    }
}

extern "C" void kernel_launch(void* const* d_in, const int* in_sizes, int n_in,
                              void* d_out, int out_size, void* d_ws, size_t ws_size,
                              hipStream_t stream) {
    const float* x   = (const float*)d_in[0];
    const int*   ei  = (const int*)d_in[1];
    const float* ea  = (const float*)d_in[2];
    const float* Wn  = (const float*)d_in[3];
    const float* bn  = (const float*)d_in[4];
    const float* Wr  = (const float*)d_in[5];
    const float* br  = (const float*)d_in[6];
    const float* Wo  = (const float*)d_in[7];
    const float* bo  = (const float*)d_in[8];
    float* out = (float*)d_out;
    unsigned short* wt = (unsigned short*)d_ws;

    const bool xbf = ws_size >= (size_t)(WOFF + XBF_SHORTS) * sizeof(unsigned short);

    prep_w<<<160, 256, 0, stream>>>(Wn, Wr, Wo, wt);
    if (xbf) {
        prep_x<<<(XBF_SHORTS / 8 + 255) / 256, 256, 0, stream>>>(x, wt + WOFF);
        edge_mlp<true><<<GRID, TPB, 0, stream>>>(x, wt + WOFF, ei, ea, bn, br, bo, wt, out);
    } else {
        edge_mlp<false><<<GRID, TPB, 0, stream>>>(x, nullptr, ei, ea, bn, br, bo, wt, out);
    }
}

// Round 5
// 289.079 us; speedup vs baseline: 3.2202x; 1.9141x over previous
//
#include <hip/hip_runtime.h>

#define E_EDGES 1600000
#define BM 64
#define TPB 512
#define NTILES (E_EDGES / BM)   // 25000 exactly
#define GRID 512
#define WOFF 40960              // shorts reserved for weights in d_ws
#define XBF_SHORTS (100000 * 64)

typedef short s16x8 __attribute__((ext_vector_type(8)));
typedef float f32x4 __attribute__((ext_vector_type(4)));

__device__ __forceinline__ unsigned short f2bf(float f) {
    unsigned int u = __builtin_bit_cast(unsigned int, f);
    u += 0x7FFFu + ((u >> 16) & 1u);   // RNE
    return (unsigned short)(u >> 16);
}

__device__ __forceinline__ s16x8 pack8(float4 a, float4 b) {
    s16x8 r;
    r[0] = (short)f2bf(a.x); r[1] = (short)f2bf(a.y);
    r[2] = (short)f2bf(a.z); r[3] = (short)f2bf(a.w);
    r[4] = (short)f2bf(b.x); r[5] = (short)f2bf(b.y);
    r[6] = (short)f2bf(b.z); r[7] = (short)f2bf(b.w);
    return r;
}

// d_ws layout (shorts): [0,16384) Wnnn^T [128o][128i]; [16384,24576) Wroot^T [128o][64i];
//                       [24576,40960) Wout^T [128o][128i]; [40960, +6.4M) x as bf16
__global__ void prep_w(const float* __restrict__ Wn, const float* __restrict__ Wr,
                       const float* __restrict__ Wo, unsigned short* __restrict__ wt) {
    int t = blockIdx.x * 256 + threadIdx.x;
    if (t < 16384) {
        int o = t >> 7, i = t & 127;
        wt[t] = f2bf(Wn[i * 128 + o]);
    } else if (t < 24576) {
        int q = t - 16384;
        int o = q >> 6, i = q & 63;
        wt[t] = f2bf(Wr[i * 128 + o]);
    } else if (t < 40960) {
        int q = t - 24576;
        int o = q >> 7, i = q & 127;
        wt[t] = f2bf(Wo[i * 128 + o]);
    }
}

__global__ void prep_x(const float* __restrict__ x, unsigned short* __restrict__ xb) {
    int i = blockIdx.x * 256 + threadIdx.x;    // 800000 chunks of 8 floats
    if (i < XBF_SHORTS / 8) {
        const float4* p = (const float4*)(x + (size_t)i * 8);
        *(s16x8*)(xb + (size_t)i * 8) = pack8(p[0], p[1]);
    }
}

// Swapped-operand MFMA: mfma(A = W^T frag [n][k], B = data frag [k][e]).
// C-frag: col(lane&15)=e, row((lane>>4)*4+j)=n -> 4 consecutive n per lane ->
// b64 hid writes, dwordx4 out stores.
// LDS tiles are chunk-major [kq][e][8 shorts]: B-frag read for (kk,q,e) is the
// 16B at (kk*4+q)*1024 + e*16 -> linear, bank-even, no swizzle needed.
template<bool XBF>
__global__ __launch_bounds__(TPB, 4) void edge_mlp(
    const float* __restrict__ x, const unsigned short* __restrict__ xb,
    const int* __restrict__ eidx, const float* __restrict__ ea,
    const float* __restrict__ bn_g, const float* __restrict__ br_g,
    const float* __restrict__ bo_g,
    const unsigned short* __restrict__ wt, float* __restrict__ out)
{
    __shared__ unsigned short sh_pair[16 * 64 * 8];  // [kq][e][8], 16 KB
    __shared__ unsigned short sh_ea[8 * 64 * 8];     // [kq][e][8],  8 KB
    __shared__ unsigned short sh_hid[16 * 64 * 8];   // [kq][e][8], 16 KB

    const int tid = threadIdx.x;
    const int w   = tid >> 6;        // wave 0..7 -> n-slice w*16
    const int ln  = tid & 63;
    const int lc  = ln & 15;
    const int q   = ln >> 4;         // 0..3
    const int lk8 = q * 8;

    // gather ownership: thread owns edge-row r; pair chunks c0,c0+1; ea chunk ec
    const int r   = tid >> 3;        // 0..63
    const int c0  = (tid & 7) * 2;   // even chunk 0..14 (c0<8: src half, else dst)
    const int ihalf = (c0 < 8) ? 0 : E_EDGES;
    const int ec  = tid & 7;

    const unsigned short* Wn = wt;
    const unsigned short* Wr = wt + 16384;
    const unsigned short* Wo = wt + 24576;

    // --- pinned weight A-fragments (40 VGPR) ---
    s16x8 wn[4], wr[2], wo[4];
    const int n0 = w * 16 + lc;
    #pragma unroll
    for (int kk = 0; kk < 4; ++kk) wn[kk] = *(const s16x8*)(Wn + n0 * 128 + kk * 32 + lk8);
    #pragma unroll
    for (int kk = 0; kk < 2; ++kk) wr[kk] = *(const s16x8*)(Wr + n0 * 64 + kk * 32 + lk8);
    #pragma unroll
    for (int kk = 0; kk < 4; ++kk) wo[kk] = *(const s16x8*)(Wo + n0 * 128 + kk * 32 + lk8);

    const int nb = w * 16 + q * 4;   // lane's 4 consecutive output features
    const float4 bn4 = *(const float4*)(bn_g + nb);
    const float4 br4 = *(const float4*)(br_g + nb);
    const float4 bo4 = *(const float4*)(bo_g + nb);

    // --- pipeline regs: tile t+1 data, tile t+2 index ---
    s16x8 pr0, pr1;                  // XBF pair chunks
    float4 pf0, pf1, pf2, pf3;       // fallback fp32 pair chunks
    float4 ef0, ef1;                 // ea 32B slice
    int ic, ic_n;

    int tile = blockIdx.x;

    // prologue: tile-0 data, tile-1 index
    ic = eidx[ihalf + tile * BM + r];
    if constexpr (XBF) {
        const s16x8* xp = (const s16x8*)(xb + (size_t)ic * 64 + (c0 & 7) * 8);
        pr0 = xp[0]; pr1 = xp[1];
    } else {
        const float4* xp = (const float4*)(x + (size_t)ic * 64 + (c0 & 7) * 8);
        pf0 = xp[0]; pf1 = xp[1]; pf2 = xp[2]; pf3 = xp[3];
    }
    {
        const float4* ep = (const float4*)(ea + (size_t)(tile * BM + r) * 64 + ec * 8);
        ef0 = ep[0]; ef1 = ep[1];
    }
    {
        int t1 = (tile + GRID < NTILES) ? tile + GRID : tile;
        ic_n = eidx[ihalf + t1 * BM + r];
    }

    for (; tile < NTILES; tile += GRID) {
        const int base = tile * BM;
        const int tn  = (tile + GRID < NTILES) ? tile + GRID : tile;
        const int tnn = (tn + GRID < NTILES) ? tn + GRID : tn;

        // --- A: drain prefetch -> LDS (chunk-major) ---
        if constexpr (XBF) {
            *(s16x8*)((char*)sh_pair + c0 * 1024 + r * 16)       = pr0;
            *(s16x8*)((char*)sh_pair + (c0 + 1) * 1024 + r * 16) = pr1;
        } else {
            *(s16x8*)((char*)sh_pair + c0 * 1024 + r * 16)       = pack8(pf0, pf1);
            *(s16x8*)((char*)sh_pair + (c0 + 1) * 1024 + r * 16) = pack8(pf2, pf3);
        }
        *(s16x8*)((char*)sh_ea + ec * 1024 + r * 16) = pack8(ef0, ef1);

        // --- C: issue tile t+1 loads (cover: D + barrier + E) ---
        ic = ic_n;
        if constexpr (XBF) {
            const s16x8* xp = (const s16x8*)(xb + (size_t)ic * 64 + (c0 & 7) * 8);
            pr0 = xp[0]; pr1 = xp[1];
        } else {
            const float4* xp = (const float4*)(x + (size_t)ic * 64 + (c0 & 7) * 8);
            pf0 = xp[0]; pf1 = xp[1]; pf2 = xp[2]; pf3 = xp[3];
        }
        {
            const float4* ep = (const float4*)(ea + (size_t)(tn * BM + r) * 64 + ec * 8);
            ef0 = ep[0]; ef1 = ep[1];
        }
        ic_n = eidx[ihalf + tnn * BM + r];   // tile t+2 index (full-tile cover)

        __syncthreads();   // barrier1: LDS pair/ea ready; hid E(t-1) reads done

        // --- D: layer 1 -> sh_hid ---
        #pragma unroll
        for (int m = 0; m < 4; ++m) {
            const int e = m * 16 + lc;
            f32x4 a1 = {0.f, 0.f, 0.f, 0.f};
            f32x4 a2 = {0.f, 0.f, 0.f, 0.f};
            #pragma unroll
            for (int kk = 0; kk < 4; ++kk) {
                s16x8 g = *(const s16x8*)((const char*)sh_pair + (kk * 4 + q) * 1024 + e * 16);
                a1 = __builtin_amdgcn_mfma_f32_16x16x32_bf16(wn[kk], g, a1, 0, 0, 0);
            }
            #pragma unroll
            for (int kk = 0; kk < 2; ++kk) {
                s16x8 g = *(const s16x8*)((const char*)sh_ea + (kk * 4 + q) * 1024 + e * 16);
                a2 = __builtin_amdgcn_mfma_f32_16x16x32_bf16(wr[kk], g, a2, 0, 0, 0);
            }
            unsigned short h0 = f2bf(fmaxf(a1[0] + bn4.x, 0.f) + fmaxf(a2[0] + br4.x, 0.f));
            unsigned short h1 = f2bf(fmaxf(a1[1] + bn4.y, 0.f) + fmaxf(a2[1] + br4.y, 0.f));
            unsigned short h2 = f2bf(fmaxf(a1[2] + bn4.z, 0.f) + fmaxf(a2[2] + br4.z, 0.f));
            unsigned short h3 = f2bf(fmaxf(a1[3] + bn4.w, 0.f) + fmaxf(a2[3] + br4.w, 0.f));
            uint2 hv;
            hv.x = (unsigned)h0 | ((unsigned)h1 << 16);
            hv.y = (unsigned)h2 | ((unsigned)h3 << 16);
            // hid chunk = (w*16+q*4)/8 = w*2 + (q>>1); byte within chunk-row = (q&1)*8
            *(uint2*)((char*)sh_hid + (w * 2 + (q >> 1)) * 1024 + e * 16 + (q & 1) * 8) = hv;
        }
        __syncthreads();   // barrier2: hid ready; pair/ea reads done before A(t+1)

        // --- E: layer 2 -> out ---
        #pragma unroll
        for (int m = 0; m < 4; ++m) {
            const int e = m * 16 + lc;
            f32x4 a3 = {0.f, 0.f, 0.f, 0.f};
            #pragma unroll
            for (int kk = 0; kk < 4; ++kk) {
                s16x8 g = *(const s16x8*)((const char*)sh_hid + (kk * 4 + q) * 1024 + e * 16);
                a3 = __builtin_amdgcn_mfma_f32_16x16x32_bf16(wo[kk], g, a3, 0, 0, 0);
            }
            float4 o;
            o.x = fmaxf(a3[0] + bo4.x, 0.f);
            o.y = fmaxf(a3[1] + bo4.y, 0.f);
            o.z = fmaxf(a3[2] + bo4.z, 0.f);
            o.w = fmaxf(a3[3] + bo4.w, 0.f);
            *(float4*)(out + (size_t)(base + e) * 128 + nb) = o;
        }
    }
}

extern "C" void kernel_launch(void* const* d_in, const int* in_sizes, int n_in,
                              void* d_out, int out_size, void* d_ws, size_t ws_size,
                              hipStream_t stream) {
    const float* x   = (const float*)d_in[0];
    const int*   ei  = (const int*)d_in[1];
    const float* ea  = (const float*)d_in[2];
    const float* Wn  = (const float*)d_in[3];
    const float* bn  = (const float*)d_in[4];
    const float* Wr  = (const float*)d_in[5];
    const float* br  = (const float*)d_in[6];
    const float* Wo  = (const float*)d_in[7];
    const float* bo  = (const float*)d_in[8];
    float* out = (float*)d_out;
    unsigned short* wt = (unsigned short*)d_ws;

    const bool xbf = ws_size >= (size_t)(WOFF + XBF_SHORTS) * sizeof(unsigned short);

    prep_w<<<160, 256, 0, stream>>>(Wn, Wr, Wo, wt);
    if (xbf) {
        prep_x<<<XBF_SHORTS / 8 / 256, 256, 0, stream>>>(x, wt + WOFF);
        edge_mlp<true><<<GRID, TPB, 0, stream>>>(x, wt + WOFF, ei, ea, bn, br, bo, wt, out);
    } else {
        edge_mlp<false><<<GRID, TPB, 0, stream>>>(x, nullptr, ei, ea, bn, br, bo, wt, out);
    }
}